// Round 5
// baseline (988.216 us; speedup 1.0000x reference)
//
#include <hip/hip_runtime.h>
#include <stdint.h>

#define S_    2048
#define HID_  2048
#define NH_   16
#define NKV_  4
#define HD_   128

using short4x = __attribute__((ext_vector_type(4))) short;
using short8  = __attribute__((ext_vector_type(8))) short;
using floatx4 = __attribute__((ext_vector_type(4))) float;

#define NEGBIG (-3.0e38f)
#define QSCL_  (0.08838834764831845f * 1.4426950408889634f)

__device__ __forceinline__ unsigned short f2bf(float x) {
  union { float f; unsigned u; } v; v.f = x;
  unsigned r = v.u + 0x7fffu + ((v.u >> 16) & 1u);
  return (unsigned short)(r >> 16);
}
__device__ __forceinline__ float bf2f(unsigned short b) {
  union { unsigned u; float f; } v; v.u = ((unsigned)b) << 16;
  return v.f;
}
__device__ __forceinline__ void ld_lds16(const void* g, void* l) {
  __builtin_amdgcn_global_load_lds(
      (const __attribute__((address_space(1))) unsigned*)g,
      (__attribute__((address_space(3))) unsigned*)l, 16, 0, 0);
}

// ---------------- fused fp32 -> bf16 convert of all three inputs ----------------
__global__ void k_cvt3(const float* __restrict__ s0, unsigned short* __restrict__ d0, int n0,
                       const float* __restrict__ s1, unsigned short* __restrict__ d1, int n1,
                       const float* __restrict__ s2, unsigned short* __restrict__ d2, int n2) {
  int i = blockIdx.x * blockDim.x + threadIdx.x;
  const float* s; unsigned short* d;
  if (i < n0) { s = s0; d = d0; }
  else if (i < n0 + n1) { s = s1; d = d1; i -= n0; }
  else { s = s2; d = d2; i -= n0 + n1; if (i >= n2) return; }
  float4 v = ((const float4*)s)[i];
  union { unsigned short us[4]; uint2 u2; } u;
  u.us[0] = f2bf(v.x); u.us[1] = f2bf(v.y); u.us[2] = f2bf(v.z); u.us[3] = f2bf(v.w);
  ((uint2*)d)[i] = u.u2;
}

// ---- bt-GEMM: C[m,n] = sum_k A[m,k]*B[n,k], 128x128 tile, BK=32 (m97 single-buf)
// EPI==0: QKV projection epilogue with FUSED RoPE. Each 128-col tile is one
// head; rotate-half partner (d <-> d+64) lives in the paired wave (wn^64) at
// the same lane/frag index. The 16KB staging LDS is dead after the K-loop and
// exactly holds one i-chunk of clamped acc (256thr x 16 f32) -> 4-chunk
// write/bar/read exchange, then out = x*cs -/+ y*sn (Q also * QSCL).
// EPI==1: plain f32 store (output projection).
template <int EPI>
__global__ void __launch_bounds__(256)
k_gemm_bt(const unsigned short* __restrict__ A, const unsigned short* __restrict__ Bw,
          unsigned short* __restrict__ Qb, unsigned short* __restrict__ Kb,
          unsigned short* __restrict__ Vt, float* __restrict__ Of,
          const int* __restrict__ pos) {
  const int K = HID_;
  __shared__ __align__(16) unsigned short smg[8192];   // As[4096] | Bs[4096]
  unsigned short* As = smg;
  unsigned short* Bs = smg + 4096;
  const int tid  = threadIdx.x;
  const int wave = tid >> 6, lane = tid & 63;
  const int quad = lane >> 4, l15 = lane & 15;
  const int wm = (wave >> 1) * 64, wn = (wave & 1) * 64;
  const int m0 = blockIdx.x * 128, n0 = blockIdx.y * 128;

  floatx4 acc[4][4] = {};

  const int srow = tid >> 2;
  const int scol = (tid & 3) * 8;
  const unsigned short* Ag0 = A  + (size_t)(m0 + srow)      * K + scol;
  const unsigned short* Ag1 = A  + (size_t)(m0 + 64 + srow) * K + scol;
  const unsigned short* Bg0 = Bw + (size_t)(n0 + srow)      * K + scol;
  const unsigned short* Bg1 = Bw + (size_t)(n0 + 64 + srow) * K + scol;
  unsigned short* lA0 = &As[tid * 8];
  unsigned short* lA1 = &As[2048 + tid * 8];
  unsigned short* lB0 = &Bs[tid * 8];
  unsigned short* lB1 = &Bs[2048 + tid * 8];

  for (int k0 = 0; k0 < K; k0 += 32) {
    __syncthreads();
    ld_lds16(Ag0 + k0, lA0);
    ld_lds16(Ag1 + k0, lA1);
    ld_lds16(Bg0 + k0, lB0);
    ld_lds16(Bg1 + k0, lB1);
    __syncthreads();
    short8 a[4], b[4];
#pragma unroll
    for (int i = 0; i < 4; i++) a[i] = *(const short8*)&As[(wm + i * 16 + l15) * 32 + quad * 8];
#pragma unroll
    for (int j = 0; j < 4; j++) b[j] = *(const short8*)&Bs[(wn + j * 16 + l15) * 32 + quad * 8];
#pragma unroll
    for (int i = 0; i < 4; i++)
#pragma unroll
      for (int j = 0; j < 4; j++)
        acc[i][j] = __builtin_amdgcn_mfma_f32_16x16x32_bf16(a[i], b[j], acc[i][j], 0, 0, 0);
  }

  if (EPI == 1) {
#pragma unroll
    for (int i = 0; i < 4; i++)
#pragma unroll
      for (int j = 0; j < 4; j++) {
        const int col = n0 + wn + j * 16 + l15;
#pragma unroll
        for (int r = 0; r < 4; r++) {
          const int row = m0 + wm + i * 16 + quad * 4 + r;
          Of[(size_t)row * HID_ + col] = acc[i][j][r];
        }
      }
    return;
  }

  if (n0 >= HID_ + NKV_ * HD_) {
    // V tile: clamp + transposed store (no rope)
#pragma unroll
    for (int i = 0; i < 4; i++)
#pragma unroll
      for (int j = 0; j < 4; j++) {
        const int col = n0 + wn + j * 16 + l15;
        const int oo = col - (HID_ + NKV_ * HD_);
        const int kvh = oo >> 7, d = oo & 127;
#pragma unroll
        for (int r = 0; r < 4; r++) {
          const int row = m0 + wm + i * 16 + quad * 4 + r;
          float x = fminf(fmaxf(acc[i][j][r], -8.0f), 8.0f);
          int bb = row >> 11, ss = row & 2047;
          Vt[((size_t)((bb * NKV_ + kvh) * HD_ + d) << 11) + ss] = f2bf(x);
        }
      }
    return;
  }

  // Q or K tile: fused RoPE epilogue (block-uniform path; barriers safe)
  const float oscale = (n0 < HID_) ? QSCL_ : 1.0f;
  float* X = (float*)smg;   // 4096 floats = 16KB, exactly one i-chunk
  float inv4[4];
#pragma unroll
  for (int j = 0; j < 4; j++)
    inv4[j] = expf(-(float)(j * 16 + l15) * (13.122363377404328f / 64.0f));

#pragma unroll
  for (int i = 0; i < 4; i++) {
    floatx4 accC[4];
    __syncthreads();   // protect previous chunk reads / K-loop LDS reads
#pragma unroll
    for (int j = 0; j < 4; j++) {
      floatx4 c;
#pragma unroll
      for (int r = 0; r < 4; r++) c[r] = fminf(fmaxf(acc[i][j][r], -8.0f), 8.0f);
      accC[j] = c;
      *(floatx4*)&X[wave * 1024 + j * 256 + lane * 4] = c;
    }
    __syncthreads();
    const int4 p4 = *(const int4*)&pos[m0 + wm + i * 16 + quad * 4];
#pragma unroll
    for (int j = 0; j < 4; j++) {
      const floatx4 pr = *(const floatx4*)&X[(wave ^ 1) * 1024 + j * 256 + lane * 4];
      const int col = n0 + wn + j * 16 + l15;
#pragma unroll
      for (int r = 0; r < 4; r++) {
        const int row = m0 + wm + i * 16 + quad * 4 + r;
        const float f = (float)((&p4.x)[r]) * inv4[j];
        const float cs = cosf(f), sn = sinf(f);
        const float x = accC[j][r], y = pr[r];
        float o = (wn == 0) ? (x * cs - y * sn) : (x * cs + y * sn);
        o *= oscale;
        if (col < HID_) Qb[(size_t)row * HID_ + col] = f2bf(o);
        else            Kb[(size_t)row * (NKV_ * HD_) + (col - HID_)] = f2bf(o);
      }
    }
  }
}

// --- flash attention v6: v5 (XOR bank swizzle) + defer-max (T13, THR=8) ------
__global__ void __launch_bounds__(256, 2)
k_attn(const unsigned short* __restrict__ Qb, const unsigned short* __restrict__ Kb,
       const unsigned short* __restrict__ Vt, unsigned short* __restrict__ AO) {
  __shared__ __align__(16) unsigned short sm[2][16384];
  __shared__ __align__(16) unsigned short Pl[4][16][88];

  const int tid  = threadIdx.x;
  const int wave = tid >> 6, lane = tid & 63;
  const int quad = lane >> 4, l15 = lane & 15;
  const int tLow  = blockIdx.x;
  const int tHigh = 31 - tLow;
  const int q0L = tLow * 64, q0H = tHigh * 64;
  const int bh = blockIdx.y;
  const int b = bh >> 4, h = bh & 15;
  const int kvh = h >> 2;

  const int srow = tid >> 2;
  const int scolz = (((tid & 3) ^ ((tid >> 3) & 3)) * 8);
  const int qoff = ((quad ^ ((l15 >> 1) & 3)) * 8);

  {
    const unsigned short* qgL = Qb + (size_t)(b * S_ + q0L + srow) * HID_ + h * HD_ + scolz;
    const unsigned short* qgH = Qb + (size_t)(b * S_ + q0H + srow) * HID_ + h * HD_ + scolz;
#pragma unroll
    for (int i = 0; i < 4; i++) ld_lds16(qgL + i * 32, &sm[0][i * 2048 + tid * 8]);
#pragma unroll
    for (int i = 0; i < 4; i++) ld_lds16(qgH + i * 32, &sm[1][i * 2048 + tid * 8]);
  }
  __syncthreads();
  short8 qaL[4], qaH[4];
#pragma unroll
  for (int c = 0; c < 4; c++) {
    qaL[c] = *(const short8*)&sm[0][(c * 64 + wave * 16 + l15) * 32 + qoff];
    qaH[c] = *(const short8*)&sm[1][(c * 64 + wave * 16 + l15) * 32 + qoff];
  }
  __syncthreads();

  floatx4 oacL[8] = {}, oacH[8] = {};
  floatx4 oacEL = {}, oacEH = {};
  float mL = NEGBIG, mH = NEGBIG;

  const unsigned short* kgb = Kb + (size_t)b * S_ * (NKV_ * HD_) + kvh * HD_ + scolz;
  const unsigned short* vgb = Vt + (size_t)(b * NKV_ + kvh) * HD_ * S_;

  unsigned short* PlW = &Pl[wave][0][0];

  short8 ones;
#pragma unroll
  for (int i = 0; i < 8; i++) ones[i] = (short)0x3F80;

  auto stage = [&](int bufI, int j) {
    unsigned short* B = &sm[bufI][0];
    const unsigned short* kg = kgb + (size_t)(j * 64 + srow) * (NKV_ * HD_);
#pragma unroll
    for (int i = 0; i < 4; i++) ld_lds16(kg + i * 32, &B[i * 2048 + tid * 8]);
#pragma unroll
    for (int i = 0; i < 4; i++) {
      int c = i >> 1, rowd = (i & 1) * 64 + srow;
      ld_lds16(vgb + (size_t)rowd * S_ + j * 64 + c * 32 + scolz,
               &B[8192 + c * 4096 + (i & 1) * 2048 + tid * 8]);
    }
  };

  // softmax: mask, running max with defer-max THR=8 (P bounded by 2^8; E,O in
  // f32 have ample headroom; final divide normalizes)
  auto softmax_tile = [&](floatx4* sc, floatx4* oac, floatx4& oacE, float& m_run,
                          int q0, int j, bool diag, short8& pa0, short8& pa1) {
    if (diag) {
      const int rowq = q0 + wave * 16 + l15;
#pragma unroll
      for (int t = 0; t < 4; t++) {
        const int kb0 = j * 64 + t * 16 + quad * 4;
#pragma unroll
        for (int r = 0; r < 4; r++)
          if (kb0 + r > rowq) sc[t][r] = NEGBIG;
      }
    }
    float mx = sc[0][0];
#pragma unroll
    for (int t = 0; t < 4; t++)
#pragma unroll
      for (int r = 0; r < 4; r++) mx = fmaxf(mx, sc[t][r]);
    mx = fmaxf(mx, __shfl_xor(mx, 16));
    mx = fmaxf(mx, __shfl_xor(mx, 32));

    const float mo = m_run;
    if (__any(mx > mo + 8.0f)) {   // defer-max: rescale only on big jumps
      m_run = fmaxf(mo, mx);
      float alpha = __builtin_amdgcn_exp2f(mo - m_run);
      float al4[4];
#pragma unroll
      for (int r = 0; r < 4; r++) al4[r] = __shfl(alpha, quad * 4 + r, 16);
#pragma unroll
      for (int t = 0; t < 8; t++)
#pragma unroll
        for (int r = 0; r < 4; r++) oac[t][r] *= al4[r];
#pragma unroll
      for (int r = 0; r < 4; r++) oacE[r] *= al4[r];
    }
#pragma unroll
    for (int t = 0; t < 4; t++) {
      short4x pk;
#pragma unroll
      for (int r = 0; r < 4; r++)
        pk[r] = (short)f2bf(__builtin_amdgcn_exp2f(sc[t][r] - m_run));
      *(short4x*)&PlW[l15 * 88 + t * 16 + quad * 4] = pk;
    }
    pa0 = *(const short8*)&PlW[l15 * 88 + quad * 8];
    pa1 = *(const short8*)&PlW[l15 * 88 + 32 + quad * 8];
  };

  auto step_two = [&](int j, const unsigned short* Kt, const unsigned short* Vts,
                      bool diagL, bool diagH) {
    floatx4 scH[4] = {}, scL[4] = {};
#pragma unroll
    for (int t = 0; t < 4; t++)
#pragma unroll
      for (int c = 0; c < 4; c++) {
        short8 ka = *(const short8*)&Kt[c * 2048 + (t * 16 + l15) * 32 + qoff];
        scH[t] = __builtin_amdgcn_mfma_f32_16x16x32_bf16(ka, qaH[c], scH[t], 0, 0, 0);
        scL[t] = __builtin_amdgcn_mfma_f32_16x16x32_bf16(ka, qaL[c], scL[t], 0, 0, 0);
      }
    short8 paH0, paH1, paL0, paL1;
    softmax_tile(scH, oacH, oacEH, mH, q0H, j, diagH, paH0, paH1);
    softmax_tile(scL, oacL, oacEL, mL, q0L, j, diagL, paL0, paL1);
#pragma unroll
    for (int t = 0; t < 8; t++) {
      short8 vb0 = *(const short8*)&Vts[(t * 16 + l15) * 32 + qoff];
      oacH[t] = __builtin_amdgcn_mfma_f32_16x16x32_bf16(paH0, vb0, oacH[t], 0, 0, 0);
      oacL[t] = __builtin_amdgcn_mfma_f32_16x16x32_bf16(paL0, vb0, oacL[t], 0, 0, 0);
      short8 vb1 = *(const short8*)&Vts[4096 + (t * 16 + l15) * 32 + qoff];
      oacH[t] = __builtin_amdgcn_mfma_f32_16x16x32_bf16(paH1, vb1, oacH[t], 0, 0, 0);
      oacL[t] = __builtin_amdgcn_mfma_f32_16x16x32_bf16(paL1, vb1, oacL[t], 0, 0, 0);
    }
    oacEH = __builtin_amdgcn_mfma_f32_16x16x32_bf16(paH0, ones, oacEH, 0, 0, 0);
    oacEH = __builtin_amdgcn_mfma_f32_16x16x32_bf16(paH1, ones, oacEH, 0, 0, 0);
    oacEL = __builtin_amdgcn_mfma_f32_16x16x32_bf16(paL0, ones, oacEL, 0, 0, 0);
    oacEL = __builtin_amdgcn_mfma_f32_16x16x32_bf16(paL1, ones, oacEL, 0, 0, 0);
  };

  auto step_one = [&](int j, const unsigned short* Kt, const unsigned short* Vts, bool diagH) {
    floatx4 scH[4] = {};
#pragma unroll
    for (int t = 0; t < 4; t++)
#pragma unroll
      for (int c = 0; c < 4; c++) {
        short8 ka = *(const short8*)&Kt[c * 2048 + (t * 16 + l15) * 32 + qoff];
        scH[t] = __builtin_amdgcn_mfma_f32_16x16x32_bf16(ka, qaH[c], scH[t], 0, 0, 0);
      }
    short8 paH0, paH1;
    softmax_tile(scH, oacH, oacEH, mH, q0H, j, diagH, paH0, paH1);
#pragma unroll
    for (int t = 0; t < 8; t++) {
      short8 vb0 = *(const short8*)&Vts[(t * 16 + l15) * 32 + qoff];
      oacH[t] = __builtin_amdgcn_mfma_f32_16x16x32_bf16(paH0, vb0, oacH[t], 0, 0, 0);
      short8 vb1 = *(const short8*)&Vts[4096 + (t * 16 + l15) * 32 + qoff];
      oacH[t] = __builtin_amdgcn_mfma_f32_16x16x32_bf16(paH1, vb1, oacH[t], 0, 0, 0);
    }
    oacEH = __builtin_amdgcn_mfma_f32_16x16x32_bf16(paH0, ones, oacEH, 0, 0, 0);
    oacEH = __builtin_amdgcn_mfma_f32_16x16x32_bf16(paH1, ones, oacEH, 0, 0, 0);
  };

  stage(0, 0);
  int cur = 0;
  for (int j = 0; j <= tHigh; ++j) {
    __syncthreads();
    if (j < tHigh) stage(cur ^ 1, j + 1);
    const unsigned short* Kt  = &sm[cur][0];
    const unsigned short* Vts = Kt + 8192;
    if (j <= tLow) step_two(j, Kt, Vts, j == tLow, j == tHigh);
    else           step_one(j, Kt, Vts, j == tHigh);
    cur ^= 1;
  }

#pragma unroll
  for (int t = 0; t < 8; t++)
#pragma unroll
    for (int r = 0; r < 4; r++) {
      int rgL = q0L + wave * 16 + quad * 4 + r;
      int rgH = q0H + wave * 16 + quad * 4 + r;
      AO[(size_t)(b * S_ + rgL) * HID_ + h * HD_ + t * 16 + l15] = f2bf(oacL[t][r] / oacEL[r]);
      AO[(size_t)(b * S_ + rgH) * HID_ + h * HD_ + t * 16 + l15] = f2bf(oacH[t][r] / oacEH[r]);
    }
}

extern "C" void kernel_launch(void* const* d_in, const int* in_sizes, int n_in,
                              void* d_out, int out_size, void* d_ws, size_t ws_size,
                              hipStream_t stream) {
  (void)in_sizes; (void)n_in; (void)out_size; (void)ws_size;
  const float* hidden = (const float*)d_in[0];
  const int*   pos    = (const int*)d_in[1];
  const float* Wqkv   = (const float*)d_in[2];
  const float* Wout   = (const float*)d_in[3];
  float* out = (float*)d_out;

  unsigned short* ws = (unsigned short*)d_ws;
  const size_t M1 = 1024 * 1024;
  unsigned short* hb  = ws;
  unsigned short* wqb = ws + 8 * M1;
  unsigned short* wob = ws + 14 * M1;
  unsigned short* Qb  = ws + 18 * M1;
  unsigned short* Kb  = ws + 26 * M1;
  unsigned short* Vt  = ws + 28 * M1;
  unsigned short* AO  = hb;

  k_cvt3<<<18432, 256, 0, stream>>>(hidden, hb, 2097152,
                                    Wqkv, wqb, 1572864,
                                    Wout, wob, 1048576);
  k_gemm_bt<0><<<dim3(32, 24), 256, 0, stream>>>(hb, wqb, Qb, Kb, Vt, nullptr, pos);
  k_attn<<<dim3(16, 32), 256, 0, stream>>>(Qb, Kb, Vt, AO);
  k_gemm_bt<1><<<dim3(32, 16), 256, 0, stream>>>(AO, wob, nullptr, nullptr, nullptr, out, nullptr);
}

// Round 8
// 353.389 us; speedup vs baseline: 2.7964x; 2.7964x over previous
//
#include <hip/hip_runtime.h>
#include <stdint.h>

#define S_    2048
#define HID_  2048
#define NH_   16
#define NKV_  4
#define HD_   128

using short4x = __attribute__((ext_vector_type(4))) short;
using short8  = __attribute__((ext_vector_type(8))) short;
using floatx4 = __attribute__((ext_vector_type(4))) float;

#define NEGBIG (-3.0e38f)
#define QSCL_  (0.08838834764831845f * 1.4426950408889634f)

__device__ __forceinline__ unsigned short f2bf(float x) {
  union { float f; unsigned u; } v; v.f = x;
  unsigned r = v.u + 0x7fffu + ((v.u >> 16) & 1u);
  return (unsigned short)(r >> 16);
}
__device__ __forceinline__ float bf2f(unsigned short b) {
  union { unsigned u; float f; } v; v.u = ((unsigned)b) << 16;
  return v.f;
}
__device__ __forceinline__ void ld_lds16(const void* g, void* l) {
  __builtin_amdgcn_global_load_lds(
      (const __attribute__((address_space(1))) unsigned*)g,
      (__attribute__((address_space(3))) unsigned*)l, 16, 0, 0);
}

// ---------------- fused fp32 -> bf16 convert of all three inputs ----------------
__global__ void k_cvt3(const float* __restrict__ s0, unsigned short* __restrict__ d0, int n0,
                       const float* __restrict__ s1, unsigned short* __restrict__ d1, int n1,
                       const float* __restrict__ s2, unsigned short* __restrict__ d2, int n2) {
  int i = blockIdx.x * blockDim.x + threadIdx.x;
  const float* s; unsigned short* d;
  if (i < n0) { s = s0; d = d0; }
  else if (i < n0 + n1) { s = s1; d = d1; i -= n0; }
  else { s = s2; d = d2; i -= n0 + n1; if (i >= n2) return; }
  float4 v = ((const float4*)s)[i];
  union { unsigned short us[4]; uint2 u2; } u;
  u.us[0] = f2bf(v.x); u.us[1] = f2bf(v.y); u.us[2] = f2bf(v.z); u.us[3] = f2bf(v.w);
  ((uint2*)d)[i] = u.u2;
}

// ---- RoPE cos/sin table: tab[m*64+d] = (cos, sin) of pos[m]*theta^(-d/64) ----
// Trig lives HERE (nothing live across the libm calls), never in the GEMM:
// R5 post-mortem - inlined cosf/sinf inside the MFMA kernel spilled the
// accumulators to scratch (2.7 GB of traffic, 795 us).
__global__ void k_tab(const int* __restrict__ pos, float2* __restrict__ tab) {
  int i = blockIdx.x * blockDim.x + threadIdx.x;   // [0, 4096*64)
  int d = i & 63, m = i >> 6;
  float p = (float)pos[m];
  float inv = expf(-(float)d * (13.122363377404328f / 64.0f));
  float f = p * inv;
  tab[i] = make_float2(cosf(f), sinf(f));
}

// ---- bt-GEMM: C[m,n] = sum_k A[m,k]*B[n,k], 128x128 tile, BK=32 (m97 single-buf)
// EPI==0: QKV projection epilogue with fused RoPE via the (cos,sin) TABLE.
// Rotate-half partner (d <-> d+64) lives in the paired wave (wn^64) at the
// same lane/frag index; exchanged through the dead 16KB staging LDS in 4
// chunks (structure correctness-verified in R5). EPI==1: plain f32 store.
template <int EPI>
__global__ void __launch_bounds__(256)
k_gemm_bt(const unsigned short* __restrict__ A, const unsigned short* __restrict__ Bw,
          unsigned short* __restrict__ Qb, unsigned short* __restrict__ Kb,
          unsigned short* __restrict__ Vt, float* __restrict__ Of,
          const float2* __restrict__ tab) {
  const int K = HID_;
  __shared__ __align__(16) unsigned short smg[8192];   // As[4096] | Bs[4096]
  unsigned short* As = smg;
  unsigned short* Bs = smg + 4096;
  const int tid  = threadIdx.x;
  const int wave = tid >> 6, lane = tid & 63;
  const int quad = lane >> 4, l15 = lane & 15;
  const int wm = (wave >> 1) * 64, wn = (wave & 1) * 64;
  const int m0 = blockIdx.x * 128, n0 = blockIdx.y * 128;

  floatx4 acc[4][4] = {};

  const int srow = tid >> 2;
  const int scol = (tid & 3) * 8;
  const unsigned short* Ag0 = A  + (size_t)(m0 + srow)      * K + scol;
  const unsigned short* Ag1 = A  + (size_t)(m0 + 64 + srow) * K + scol;
  const unsigned short* Bg0 = Bw + (size_t)(n0 + srow)      * K + scol;
  const unsigned short* Bg1 = Bw + (size_t)(n0 + 64 + srow) * K + scol;
  unsigned short* lA0 = &As[tid * 8];
  unsigned short* lA1 = &As[2048 + tid * 8];
  unsigned short* lB0 = &Bs[tid * 8];
  unsigned short* lB1 = &Bs[2048 + tid * 8];

  for (int k0 = 0; k0 < K; k0 += 32) {
    __syncthreads();
    ld_lds16(Ag0 + k0, lA0);
    ld_lds16(Ag1 + k0, lA1);
    ld_lds16(Bg0 + k0, lB0);
    ld_lds16(Bg1 + k0, lB1);
    __syncthreads();
    short8 a[4], b[4];
#pragma unroll
    for (int i = 0; i < 4; i++) a[i] = *(const short8*)&As[(wm + i * 16 + l15) * 32 + quad * 8];
#pragma unroll
    for (int j = 0; j < 4; j++) b[j] = *(const short8*)&Bs[(wn + j * 16 + l15) * 32 + quad * 8];
#pragma unroll
    for (int i = 0; i < 4; i++)
#pragma unroll
      for (int j = 0; j < 4; j++)
        acc[i][j] = __builtin_amdgcn_mfma_f32_16x16x32_bf16(a[i], b[j], acc[i][j], 0, 0, 0);
  }

  if (EPI == 1) {
#pragma unroll
    for (int i = 0; i < 4; i++)
#pragma unroll
      for (int j = 0; j < 4; j++) {
        const int col = n0 + wn + j * 16 + l15;
#pragma unroll
        for (int r = 0; r < 4; r++) {
          const int row = m0 + wm + i * 16 + quad * 4 + r;
          Of[(size_t)row * HID_ + col] = acc[i][j][r];
        }
      }
    return;
  }

  if (n0 >= HID_ + NKV_ * HD_) {
    // V tile: clamp + transposed store (no rope)
#pragma unroll
    for (int i = 0; i < 4; i++)
#pragma unroll
      for (int j = 0; j < 4; j++) {
        const int col = n0 + wn + j * 16 + l15;
        const int oo = col - (HID_ + NKV_ * HD_);
        const int kvh = oo >> 7, d = oo & 127;
#pragma unroll
        for (int r = 0; r < 4; r++) {
          const int row = m0 + wm + i * 16 + quad * 4 + r;
          float x = fminf(fmaxf(acc[i][j][r], -8.0f), 8.0f);
          int bb = row >> 11, ss = row & 2047;
          Vt[((size_t)((bb * NKV_ + kvh) * HD_ + d) << 11) + ss] = f2bf(x);
        }
      }
    return;
  }

  // Q or K tile: fused RoPE epilogue (block-uniform path; barriers safe)
  const float oscale = (n0 < HID_) ? QSCL_ : 1.0f;
  float* X = (float*)smg;   // 4096 floats = 16KB, exactly one i-chunk

#pragma unroll
  for (int i = 0; i < 4; i++) {
    floatx4 accC[4];
    __syncthreads();   // protect previous chunk reads / K-loop LDS reads
#pragma unroll
    for (int j = 0; j < 4; j++) {
      floatx4 c;
#pragma unroll
      for (int r = 0; r < 4; r++) c[r] = fminf(fmaxf(acc[i][j][r], -8.0f), 8.0f);
      accC[j] = c;
      *(floatx4*)&X[wave * 1024 + j * 256 + lane * 4] = c;
    }
    __syncthreads();
#pragma unroll
    for (int j = 0; j < 4; j++) {
      const floatx4 pr = *(const floatx4*)&X[(wave ^ 1) * 1024 + j * 256 + lane * 4];
      const int col = n0 + wn + j * 16 + l15;
      const int dd = j * 16 + l15;   // freq-pair index (same for wn=0 and 64)
#pragma unroll
      for (int r = 0; r < 4; r++) {
        const int row = m0 + wm + i * 16 + quad * 4 + r;
        const float2 t = tab[(size_t)row * 64 + dd];
        const float x = accC[j][r], y = pr[r];
        float o = (wn == 0) ? (x * t.x - y * t.y) : (x * t.x + y * t.y);
        o *= oscale;
        if (col < HID_) Qb[(size_t)row * HID_ + col] = f2bf(o);
        else            Kb[(size_t)row * (NKV_ * HD_) + (col - HID_)] = f2bf(o);
      }
    }
  }
}

// --- flash attention v6: XOR bank swizzle + defer-max (T13, THR=8) -----------
__global__ void __launch_bounds__(256, 2)
k_attn(const unsigned short* __restrict__ Qb, const unsigned short* __restrict__ Kb,
       const unsigned short* __restrict__ Vt, unsigned short* __restrict__ AO) {
  __shared__ __align__(16) unsigned short sm[2][16384];
  __shared__ __align__(16) unsigned short Pl[4][16][88];

  const int tid  = threadIdx.x;
  const int wave = tid >> 6, lane = tid & 63;
  const int quad = lane >> 4, l15 = lane & 15;
  const int tLow  = blockIdx.x;
  const int tHigh = 31 - tLow;
  const int q0L = tLow * 64, q0H = tHigh * 64;
  const int bh = blockIdx.y;
  const int b = bh >> 4, h = bh & 15;
  const int kvh = h >> 2;

  const int srow = tid >> 2;
  const int scolz = (((tid & 3) ^ ((tid >> 3) & 3)) * 8);
  const int qoff = ((quad ^ ((l15 >> 1) & 3)) * 8);

  {
    const unsigned short* qgL = Qb + (size_t)(b * S_ + q0L + srow) * HID_ + h * HD_ + scolz;
    const unsigned short* qgH = Qb + (size_t)(b * S_ + q0H + srow) * HID_ + h * HD_ + scolz;
#pragma unroll
    for (int i = 0; i < 4; i++) ld_lds16(qgL + i * 32, &sm[0][i * 2048 + tid * 8]);
#pragma unroll
    for (int i = 0; i < 4; i++) ld_lds16(qgH + i * 32, &sm[1][i * 2048 + tid * 8]);
  }
  __syncthreads();
  short8 qaL[4], qaH[4];
#pragma unroll
  for (int c = 0; c < 4; c++) {
    qaL[c] = *(const short8*)&sm[0][(c * 64 + wave * 16 + l15) * 32 + qoff];
    qaH[c] = *(const short8*)&sm[1][(c * 64 + wave * 16 + l15) * 32 + qoff];
  }
  __syncthreads();

  floatx4 oacL[8] = {}, oacH[8] = {};
  floatx4 oacEL = {}, oacEH = {};
  float mL = NEGBIG, mH = NEGBIG;

  const unsigned short* kgb = Kb + (size_t)b * S_ * (NKV_ * HD_) + kvh * HD_ + scolz;
  const unsigned short* vgb = Vt + (size_t)(b * NKV_ + kvh) * HD_ * S_;

  unsigned short* PlW = &Pl[wave][0][0];

  short8 ones;
#pragma unroll
  for (int i = 0; i < 8; i++) ones[i] = (short)0x3F80;

  auto stage = [&](int bufI, int j) {
    unsigned short* B = &sm[bufI][0];
    const unsigned short* kg = kgb + (size_t)(j * 64 + srow) * (NKV_ * HD_);
#pragma unroll
    for (int i = 0; i < 4; i++) ld_lds16(kg + i * 32, &B[i * 2048 + tid * 8]);
#pragma unroll
    for (int i = 0; i < 4; i++) {
      int c = i >> 1, rowd = (i & 1) * 64 + srow;
      ld_lds16(vgb + (size_t)rowd * S_ + j * 64 + c * 32 + scolz,
               &B[8192 + c * 4096 + (i & 1) * 2048 + tid * 8]);
    }
  };

  auto softmax_tile = [&](floatx4* sc, floatx4* oac, floatx4& oacE, float& m_run,
                          int q0, int j, bool diag, short8& pa0, short8& pa1) {
    if (diag) {
      const int rowq = q0 + wave * 16 + l15;
#pragma unroll
      for (int t = 0; t < 4; t++) {
        const int kb0 = j * 64 + t * 16 + quad * 4;
#pragma unroll
        for (int r = 0; r < 4; r++)
          if (kb0 + r > rowq) sc[t][r] = NEGBIG;
      }
    }
    float mx = sc[0][0];
#pragma unroll
    for (int t = 0; t < 4; t++)
#pragma unroll
      for (int r = 0; r < 4; r++) mx = fmaxf(mx, sc[t][r]);
    mx = fmaxf(mx, __shfl_xor(mx, 16));
    mx = fmaxf(mx, __shfl_xor(mx, 32));

    const float mo = m_run;
    if (__any(mx > mo + 8.0f)) {   // defer-max: rescale only on big jumps
      m_run = fmaxf(mo, mx);
      float alpha = __builtin_amdgcn_exp2f(mo - m_run);
      float al4[4];
#pragma unroll
      for (int r = 0; r < 4; r++) al4[r] = __shfl(alpha, quad * 4 + r, 16);
#pragma unroll
      for (int t = 0; t < 8; t++)
#pragma unroll
        for (int r = 0; r < 4; r++) oac[t][r] *= al4[r];
#pragma unroll
      for (int r = 0; r < 4; r++) oacE[r] *= al4[r];
    }
#pragma unroll
    for (int t = 0; t < 4; t++) {
      short4x pk;
#pragma unroll
      for (int r = 0; r < 4; r++)
        pk[r] = (short)f2bf(__builtin_amdgcn_exp2f(sc[t][r] - m_run));
      *(short4x*)&PlW[l15 * 88 + t * 16 + quad * 4] = pk;
    }
    pa0 = *(const short8*)&PlW[l15 * 88 + quad * 8];
    pa1 = *(const short8*)&PlW[l15 * 88 + 32 + quad * 8];
  };

  auto step_two = [&](int j, const unsigned short* Kt, const unsigned short* Vts,
                      bool diagL, bool diagH) {
    floatx4 scH[4] = {}, scL[4] = {};
#pragma unroll
    for (int t = 0; t < 4; t++)
#pragma unroll
      for (int c = 0; c < 4; c++) {
        short8 ka = *(const short8*)&Kt[c * 2048 + (t * 16 + l15) * 32 + qoff];
        scH[t] = __builtin_amdgcn_mfma_f32_16x16x32_bf16(ka, qaH[c], scH[t], 0, 0, 0);
        scL[t] = __builtin_amdgcn_mfma_f32_16x16x32_bf16(ka, qaL[c], scL[t], 0, 0, 0);
      }
    short8 paH0, paH1, paL0, paL1;
    softmax_tile(scH, oacH, oacEH, mH, q0H, j, diagH, paH0, paH1);
    softmax_tile(scL, oacL, oacEL, mL, q0L, j, diagL, paL0, paL1);
#pragma unroll
    for (int t = 0; t < 8; t++) {
      short8 vb0 = *(const short8*)&Vts[(t * 16 + l15) * 32 + qoff];
      oacH[t] = __builtin_amdgcn_mfma_f32_16x16x32_bf16(paH0, vb0, oacH[t], 0, 0, 0);
      oacL[t] = __builtin_amdgcn_mfma_f32_16x16x32_bf16(paL0, vb0, oacL[t], 0, 0, 0);
      short8 vb1 = *(const short8*)&Vts[4096 + (t * 16 + l15) * 32 + qoff];
      oacH[t] = __builtin_amdgcn_mfma_f32_16x16x32_bf16(paH1, vb1, oacH[t], 0, 0, 0);
      oacL[t] = __builtin_amdgcn_mfma_f32_16x16x32_bf16(paL1, vb1, oacL[t], 0, 0, 0);
    }
    oacEH = __builtin_amdgcn_mfma_f32_16x16x32_bf16(paH0, ones, oacEH, 0, 0, 0);
    oacEH = __builtin_amdgcn_mfma_f32_16x16x32_bf16(paH1, ones, oacEH, 0, 0, 0);
    oacEL = __builtin_amdgcn_mfma_f32_16x16x32_bf16(paL0, ones, oacEL, 0, 0, 0);
    oacEL = __builtin_amdgcn_mfma_f32_16x16x32_bf16(paL1, ones, oacEL, 0, 0, 0);
  };

  auto step_one = [&](int j, const unsigned short* Kt, const unsigned short* Vts, bool diagH) {
    floatx4 scH[4] = {};
#pragma unroll
    for (int t = 0; t < 4; t++)
#pragma unroll
      for (int c = 0; c < 4; c++) {
        short8 ka = *(const short8*)&Kt[c * 2048 + (t * 16 + l15) * 32 + qoff];
        scH[t] = __builtin_amdgcn_mfma_f32_16x16x32_bf16(ka, qaH[c], scH[t], 0, 0, 0);
      }
    short8 paH0, paH1;
    softmax_tile(scH, oacH, oacEH, mH, q0H, j, diagH, paH0, paH1);
#pragma unroll
    for (int t = 0; t < 8; t++) {
      short8 vb0 = *(const short8*)&Vts[(t * 16 + l15) * 32 + qoff];
      oacH[t] = __builtin_amdgcn_mfma_f32_16x16x32_bf16(paH0, vb0, oacH[t], 0, 0, 0);
      short8 vb1 = *(const short8*)&Vts[4096 + (t * 16 + l15) * 32 + qoff];
      oacH[t] = __builtin_amdgcn_mfma_f32_16x16x32_bf16(paH1, vb1, oacH[t], 0, 0, 0);
    }
    oacEH = __builtin_amdgcn_mfma_f32_16x16x32_bf16(paH0, ones, oacEH, 0, 0, 0);
    oacEH = __builtin_amdgcn_mfma_f32_16x16x32_bf16(paH1, ones, oacEH, 0, 0, 0);
  };

  stage(0, 0);
  int cur = 0;
  for (int j = 0; j <= tHigh; ++j) {
    __syncthreads();
    if (j < tHigh) stage(cur ^ 1, j + 1);
    const unsigned short* Kt  = &sm[cur][0];
    const unsigned short* Vts = Kt + 8192;
    if (j <= tLow) step_two(j, Kt, Vts, j == tLow, j == tHigh);
    else           step_one(j, Kt, Vts, j == tHigh);
    cur ^= 1;
  }

#pragma unroll
  for (int t = 0; t < 8; t++)
#pragma unroll
    for (int r = 0; r < 4; r++) {
      int rgL = q0L + wave * 16 + quad * 4 + r;
      int rgH = q0H + wave * 16 + quad * 4 + r;
      AO[(size_t)(b * S_ + rgL) * HID_ + h * HD_ + t * 16 + l15] = f2bf(oacL[t][r] / oacEL[r]);
      AO[(size_t)(b * S_ + rgH) * HID_ + h * HD_ + t * 16 + l15] = f2bf(oacH[t][r] / oacEH[r]);
    }
}

extern "C" void kernel_launch(void* const* d_in, const int* in_sizes, int n_in,
                              void* d_out, int out_size, void* d_ws, size_t ws_size,
                              hipStream_t stream) {
  (void)in_sizes; (void)n_in; (void)out_size; (void)ws_size;
  const float* hidden = (const float*)d_in[0];
  const int*   pos    = (const int*)d_in[1];
  const float* Wqkv   = (const float*)d_in[2];
  const float* Wout   = (const float*)d_in[3];
  float* out = (float*)d_out;

  unsigned short* ws = (unsigned short*)d_ws;
  const size_t M1 = 1024 * 1024;
  unsigned short* hb  = ws;
  unsigned short* wqb = ws + 8 * M1;
  unsigned short* wob = ws + 14 * M1;
  unsigned short* Qb  = ws + 18 * M1;
  unsigned short* Kb  = ws + 26 * M1;
  unsigned short* Vt  = ws + 28 * M1;
  float2*         tab = (float2*)(ws + 30 * M1);   // 4096*64*8B = 2MB
  unsigned short* AO  = hb;

  k_cvt3<<<18432, 256, 0, stream>>>(hidden, hb, 2097152,
                                    Wqkv, wqb, 1572864,
                                    Wout, wob, 1048576);
  k_tab<<<1024, 256, 0, stream>>>(pos, tab);
  k_gemm_bt<0><<<dim3(32, 24), 256, 0, stream>>>(hb, wqb, Qb, Kb, Vt, nullptr, tab);
  k_attn<<<dim3(16, 32), 256, 0, stream>>>(Qb, Kb, Vt, AO);
  k_gemm_bt<1><<<dim3(32, 16), 256, 0, stream>>>(AO, wob, nullptr, nullptr, nullptr, out, nullptr);
}

// Round 9
// 334.731 us; speedup vs baseline: 2.9523x; 1.0557x over previous
//
#include <hip/hip_runtime.h>
#include <stdint.h>

#define S_    2048
#define HID_  2048
#define NH_   16
#define NKV_  4
#define HD_   128

using short4x = __attribute__((ext_vector_type(4))) short;
using short8  = __attribute__((ext_vector_type(8))) short;
using floatx4 = __attribute__((ext_vector_type(4))) float;

#define NEGBIG (-3.0e38f)
#define QSCL_  (0.08838834764831845f * 1.4426950408889634f)

__device__ __forceinline__ unsigned short f2bf(float x) {
  union { float f; unsigned u; } v; v.f = x;
  unsigned r = v.u + 0x7fffu + ((v.u >> 16) & 1u);
  return (unsigned short)(r >> 16);
}
__device__ __forceinline__ void ld_lds16(const void* g, void* l) {
  __builtin_amdgcn_global_load_lds(
      (const __attribute__((address_space(1))) unsigned*)g,
      (__attribute__((address_space(3))) unsigned*)l, 16, 0, 0);
}

// ---------------- fused fp32 -> bf16 convert of all three inputs ----------------
__global__ void k_cvt3(const float* __restrict__ s0, unsigned short* __restrict__ d0, int n0,
                       const float* __restrict__ s1, unsigned short* __restrict__ d1, int n1,
                       const float* __restrict__ s2, unsigned short* __restrict__ d2, int n2) {
  int i = blockIdx.x * blockDim.x + threadIdx.x;
  const float* s; unsigned short* d;
  if (i < n0) { s = s0; d = d0; }
  else if (i < n0 + n1) { s = s1; d = d1; i -= n0; }
  else { s = s2; d = d2; i -= n0 + n1; if (i >= n2) return; }
  float4 v = ((const float4*)s)[i];
  union { unsigned short us[4]; uint2 u2; } u;
  u.us[0] = f2bf(v.x); u.us[1] = f2bf(v.y); u.us[2] = f2bf(v.z); u.us[3] = f2bf(v.w);
  ((uint2*)d)[i] = u.u2;
}

// ---- RoPE cos/sin table: tab[m*64+d] = (cos, sin) of pos[m]*theta^(-d/64) ----
// Trig lives HERE (R5 post-mortem: libm trig inlined into the MFMA kernel
// spilled the accumulators; 2.7 GB scratch traffic, 795 us).
__global__ void k_tab(const int* __restrict__ pos, float2* __restrict__ tab) {
  int i = blockIdx.x * blockDim.x + threadIdx.x;   // [0, 4096*64)
  int d = i & 63, m = i >> 6;
  float p = (float)pos[m];
  float inv = expf(-(float)d * (13.122363377404328f / 64.0f));
  float f = p * inv;
  tab[i] = make_float2(cosf(f), sinf(f));
}

// ---- bt-GEMM: C[m,n] = sum_k A[m,k]*B[n,k], 128x128 tile, BK=32 (m97 single-buf)
// Column-interleaved wave mapping: wave owns cols {c, c+16, c+64, c+80},
// c=(wave&1)*32, so the RoPE rotate pair (d, d+64) is (acc[i][j], acc[i][j+2])
// IN-THREAD. R8 post-mortem: the cross-wave LDS exchange epilogue cost ~50us
// (8 barriers + 64 tab loads/thread); this removes it entirely.
// EPI==0: QKV + clamp + in-thread RoPE (Q scaled). EPI==1: plain f32 store.
template <int EPI>
__global__ void __launch_bounds__(256)
k_gemm_bt(const unsigned short* __restrict__ A, const unsigned short* __restrict__ Bw,
          unsigned short* __restrict__ Qb, unsigned short* __restrict__ Kb,
          unsigned short* __restrict__ Vt, float* __restrict__ Of,
          const float2* __restrict__ tab) {
  const int K = HID_;
  __shared__ __align__(16) unsigned short As[128 * 32];
  __shared__ __align__(16) unsigned short Bs[128 * 32];
  const int tid  = threadIdx.x;
  const int wave = tid >> 6, lane = tid & 63;
  const int quad = lane >> 4, l15 = lane & 15;
  const int wm = (wave >> 1) * 64;
  const int bc2 = (wave & 1) * 32;   // column sub-block base
  const int m0 = blockIdx.x * 128, n0 = blockIdx.y * 128;

  floatx4 acc[4][4] = {};

  const int srow = tid >> 2;
  const int scol = (tid & 3) * 8;
  const unsigned short* Ag0 = A  + (size_t)(m0 + srow)      * K + scol;
  const unsigned short* Ag1 = A  + (size_t)(m0 + 64 + srow) * K + scol;
  const unsigned short* Bg0 = Bw + (size_t)(n0 + srow)      * K + scol;
  const unsigned short* Bg1 = Bw + (size_t)(n0 + 64 + srow) * K + scol;
  unsigned short* lA0 = &As[tid * 8];
  unsigned short* lA1 = &As[2048 + tid * 8];
  unsigned short* lB0 = &Bs[tid * 8];
  unsigned short* lB1 = &Bs[2048 + tid * 8];

  for (int k0 = 0; k0 < K; k0 += 32) {
    __syncthreads();
    ld_lds16(Ag0 + k0, lA0);
    ld_lds16(Ag1 + k0, lA1);
    ld_lds16(Bg0 + k0, lB0);
    ld_lds16(Bg1 + k0, lB1);
    __syncthreads();
    short8 a[4], b[4];
#pragma unroll
    for (int i = 0; i < 4; i++) a[i] = *(const short8*)&As[(wm + i * 16 + l15) * 32 + quad * 8];
#pragma unroll
    for (int j = 0; j < 4; j++) {
      const int brow = bc2 + (j & 1) * 16 + (j >> 1) * 64;   // interleaved col map
      b[j] = *(const short8*)&Bs[(brow + l15) * 32 + quad * 8];
    }
#pragma unroll
    for (int i = 0; i < 4; i++)
#pragma unroll
      for (int j = 0; j < 4; j++)
        acc[i][j] = __builtin_amdgcn_mfma_f32_16x16x32_bf16(a[i], b[j], acc[i][j], 0, 0, 0);
  }

  if (EPI == 1) {
#pragma unroll
    for (int i = 0; i < 4; i++)
#pragma unroll
      for (int j = 0; j < 4; j++) {
        const int col = n0 + bc2 + (j & 1) * 16 + (j >> 1) * 64 + l15;
#pragma unroll
        for (int r = 0; r < 4; r++) {
          const int row = m0 + wm + i * 16 + quad * 4 + r;
          Of[(size_t)row * HID_ + col] = acc[i][j][r];
        }
      }
    return;
  }

  if (n0 >= HID_ + NKV_ * HD_) {
    // V tile: clamp + transposed store (no rope)
#pragma unroll
    for (int i = 0; i < 4; i++)
#pragma unroll
      for (int j = 0; j < 4; j++) {
        const int col = n0 + bc2 + (j & 1) * 16 + (j >> 1) * 64 + l15;
        const int oo = col - (HID_ + NKV_ * HD_);
        const int kvh = oo >> 7, d = oo & 127;
#pragma unroll
        for (int r = 0; r < 4; r++) {
          const int row = m0 + wm + i * 16 + quad * 4 + r;
          float x = fminf(fmaxf(acc[i][j][r], -8.0f), 8.0f);
          int bb = row >> 11, ss = row & 2047;
          Vt[((size_t)((bb * NKV_ + kvh) * HD_ + d) << 11) + ss] = f2bf(x);
        }
      }
    return;
  }

  // Q or K tile: in-thread RoPE (pair = acc[i][j], acc[i][j+2]); block-uniform
  const bool isQ = (n0 < HID_);
  const float oscale = isQ ? QSCL_ : 1.0f;
#pragma unroll
  for (int i = 0; i < 4; i++) {
    const int rowb = m0 + wm + i * 16 + quad * 4;
#pragma unroll
    for (int j = 0; j < 2; j++) {
      const int dlo = bc2 + j * 16 + l15;   // in-head freq index, [0,64)
#pragma unroll
      for (int r = 0; r < 4; r++) {
        const int row = rowb + r;
        const float2 t = tab[(size_t)row * 64 + dlo];
        const float x = fminf(fmaxf(acc[i][j][r],     -8.0f), 8.0f);
        const float y = fminf(fmaxf(acc[i][j + 2][r], -8.0f), 8.0f);
        const float lo = (x * t.x - y * t.y) * oscale;
        const float hi = (y * t.x + x * t.y) * oscale;
        if (isQ) {
          Qb[(size_t)row * HID_ + n0 + dlo]      = f2bf(lo);
          Qb[(size_t)row * HID_ + n0 + dlo + 64] = f2bf(hi);
        } else {
          const int cb = n0 - HID_;
          Kb[(size_t)row * (NKV_ * HD_) + cb + dlo]      = f2bf(lo);
          Kb[(size_t)row * (NKV_ * HD_) + cb + dlo + 64] = f2bf(hi);
        }
      }
    }
  }
}

// --- flash attention v6: XOR bank swizzle + defer-max (T13, THR=8) -----------
__global__ void __launch_bounds__(256, 2)
k_attn(const unsigned short* __restrict__ Qb, const unsigned short* __restrict__ Kb,
       const unsigned short* __restrict__ Vt, unsigned short* __restrict__ AO) {
  __shared__ __align__(16) unsigned short sm[2][16384];
  __shared__ __align__(16) unsigned short Pl[4][16][88];

  const int tid  = threadIdx.x;
  const int wave = tid >> 6, lane = tid & 63;
  const int quad = lane >> 4, l15 = lane & 15;
  const int tLow  = blockIdx.x;
  const int tHigh = 31 - tLow;
  const int q0L = tLow * 64, q0H = tHigh * 64;
  const int bh = blockIdx.y;
  const int b = bh >> 4, h = bh & 15;
  const int kvh = h >> 2;

  const int srow = tid >> 2;
  const int scolz = (((tid & 3) ^ ((tid >> 3) & 3)) * 8);
  const int qoff = ((quad ^ ((l15 >> 1) & 3)) * 8);

  {
    const unsigned short* qgL = Qb + (size_t)(b * S_ + q0L + srow) * HID_ + h * HD_ + scolz;
    const unsigned short* qgH = Qb + (size_t)(b * S_ + q0H + srow) * HID_ + h * HD_ + scolz;
#pragma unroll
    for (int i = 0; i < 4; i++) ld_lds16(qgL + i * 32, &sm[0][i * 2048 + tid * 8]);
#pragma unroll
    for (int i = 0; i < 4; i++) ld_lds16(qgH + i * 32, &sm[1][i * 2048 + tid * 8]);
  }
  __syncthreads();
  short8 qaL[4], qaH[4];
#pragma unroll
  for (int c = 0; c < 4; c++) {
    qaL[c] = *(const short8*)&sm[0][(c * 64 + wave * 16 + l15) * 32 + qoff];
    qaH[c] = *(const short8*)&sm[1][(c * 64 + wave * 16 + l15) * 32 + qoff];
  }
  __syncthreads();

  floatx4 oacL[8] = {}, oacH[8] = {};
  floatx4 oacEL = {}, oacEH = {};
  float mL = NEGBIG, mH = NEGBIG;

  const unsigned short* kgb = Kb + (size_t)b * S_ * (NKV_ * HD_) + kvh * HD_ + scolz;
  const unsigned short* vgb = Vt + (size_t)(b * NKV_ + kvh) * HD_ * S_;

  unsigned short* PlW = &Pl[wave][0][0];

  short8 ones;
#pragma unroll
  for (int i = 0; i < 8; i++) ones[i] = (short)0x3F80;

  auto stage = [&](int bufI, int j) {
    unsigned short* B = &sm[bufI][0];
    const unsigned short* kg = kgb + (size_t)(j * 64 + srow) * (NKV_ * HD_);
#pragma unroll
    for (int i = 0; i < 4; i++) ld_lds16(kg + i * 32, &B[i * 2048 + tid * 8]);
#pragma unroll
    for (int i = 0; i < 4; i++) {
      int c = i >> 1, rowd = (i & 1) * 64 + srow;
      ld_lds16(vgb + (size_t)rowd * S_ + j * 64 + c * 32 + scolz,
               &B[8192 + c * 4096 + (i & 1) * 2048 + tid * 8]);
    }
  };

  auto softmax_tile = [&](floatx4* sc, floatx4* oac, floatx4& oacE, float& m_run,
                          int q0, int j, bool diag, short8& pa0, short8& pa1) {
    if (diag) {
      const int rowq = q0 + wave * 16 + l15;
#pragma unroll
      for (int t = 0; t < 4; t++) {
        const int kb0 = j * 64 + t * 16 + quad * 4;
#pragma unroll
        for (int r = 0; r < 4; r++)
          if (kb0 + r > rowq) sc[t][r] = NEGBIG;
      }
    }
    float mx = sc[0][0];
#pragma unroll
    for (int t = 0; t < 4; t++)
#pragma unroll
      for (int r = 0; r < 4; r++) mx = fmaxf(mx, sc[t][r]);
    mx = fmaxf(mx, __shfl_xor(mx, 16));
    mx = fmaxf(mx, __shfl_xor(mx, 32));

    const float mo = m_run;
    if (__any(mx > mo + 8.0f)) {   // defer-max: rescale only on big jumps
      m_run = fmaxf(mo, mx);
      float alpha = __builtin_amdgcn_exp2f(mo - m_run);
      float al4[4];
#pragma unroll
      for (int r = 0; r < 4; r++) al4[r] = __shfl(alpha, quad * 4 + r, 16);
#pragma unroll
      for (int t = 0; t < 8; t++)
#pragma unroll
        for (int r = 0; r < 4; r++) oac[t][r] *= al4[r];
#pragma unroll
      for (int r = 0; r < 4; r++) oacE[r] *= al4[r];
    }
#pragma unroll
    for (int t = 0; t < 4; t++) {
      short4x pk;
#pragma unroll
      for (int r = 0; r < 4; r++)
        pk[r] = (short)f2bf(__builtin_amdgcn_exp2f(sc[t][r] - m_run));
      *(short4x*)&PlW[l15 * 88 + t * 16 + quad * 4] = pk;
    }
    pa0 = *(const short8*)&PlW[l15 * 88 + quad * 8];
    pa1 = *(const short8*)&PlW[l15 * 88 + 32 + quad * 8];
  };

  auto step_two = [&](int j, const unsigned short* Kt, const unsigned short* Vts,
                      bool diagL, bool diagH) {
    floatx4 scH[4] = {}, scL[4] = {};
#pragma unroll
    for (int t = 0; t < 4; t++)
#pragma unroll
      for (int c = 0; c < 4; c++) {
        short8 ka = *(const short8*)&Kt[c * 2048 + (t * 16 + l15) * 32 + qoff];
        scH[t] = __builtin_amdgcn_mfma_f32_16x16x32_bf16(ka, qaH[c], scH[t], 0, 0, 0);
        scL[t] = __builtin_amdgcn_mfma_f32_16x16x32_bf16(ka, qaL[c], scL[t], 0, 0, 0);
      }
    short8 paH0, paH1, paL0, paL1;
    softmax_tile(scH, oacH, oacEH, mH, q0H, j, diagH, paH0, paH1);
    softmax_tile(scL, oacL, oacEL, mL, q0L, j, diagL, paL0, paL1);
#pragma unroll
    for (int t = 0; t < 8; t++) {
      short8 vb0 = *(const short8*)&Vts[(t * 16 + l15) * 32 + qoff];
      oacH[t] = __builtin_amdgcn_mfma_f32_16x16x32_bf16(paH0, vb0, oacH[t], 0, 0, 0);
      oacL[t] = __builtin_amdgcn_mfma_f32_16x16x32_bf16(paL0, vb0, oacL[t], 0, 0, 0);
      short8 vb1 = *(const short8*)&Vts[4096 + (t * 16 + l15) * 32 + qoff];
      oacH[t] = __builtin_amdgcn_mfma_f32_16x16x32_bf16(paH1, vb1, oacH[t], 0, 0, 0);
      oacL[t] = __builtin_amdgcn_mfma_f32_16x16x32_bf16(paL1, vb1, oacL[t], 0, 0, 0);
    }
    oacEH = __builtin_amdgcn_mfma_f32_16x16x32_bf16(paH0, ones, oacEH, 0, 0, 0);
    oacEH = __builtin_amdgcn_mfma_f32_16x16x32_bf16(paH1, ones, oacEH, 0, 0, 0);
    oacEL = __builtin_amdgcn_mfma_f32_16x16x32_bf16(paL0, ones, oacEL, 0, 0, 0);
    oacEL = __builtin_amdgcn_mfma_f32_16x16x32_bf16(paL1, ones, oacEL, 0, 0, 0);
  };

  auto step_one = [&](int j, const unsigned short* Kt, const unsigned short* Vts, bool diagH) {
    floatx4 scH[4] = {};
#pragma unroll
    for (int t = 0; t < 4; t++)
#pragma unroll
      for (int c = 0; c < 4; c++) {
        short8 ka = *(const short8*)&Kt[c * 2048 + (t * 16 + l15) * 32 + qoff];
        scH[t] = __builtin_amdgcn_mfma_f32_16x16x32_bf16(ka, qaH[c], scH[t], 0, 0, 0);
      }
    short8 paH0, paH1;
    softmax_tile(scH, oacH, oacEH, mH, q0H, j, diagH, paH0, paH1);
#pragma unroll
    for (int t = 0; t < 8; t++) {
      short8 vb0 = *(const short8*)&Vts[(t * 16 + l15) * 32 + qoff];
      oacH[t] = __builtin_amdgcn_mfma_f32_16x16x32_bf16(paH0, vb0, oacH[t], 0, 0, 0);
      short8 vb1 = *(const short8*)&Vts[4096 + (t * 16 + l15) * 32 + qoff];
      oacH[t] = __builtin_amdgcn_mfma_f32_16x16x32_bf16(paH1, vb1, oacH[t], 0, 0, 0);
    }
    oacEH = __builtin_amdgcn_mfma_f32_16x16x32_bf16(paH0, ones, oacEH, 0, 0, 0);
    oacEH = __builtin_amdgcn_mfma_f32_16x16x32_bf16(paH1, ones, oacEH, 0, 0, 0);
  };

  stage(0, 0);
  int cur = 0;
  for (int j = 0; j <= tHigh; ++j) {
    __syncthreads();
    if (j < tHigh) stage(cur ^ 1, j + 1);
    const unsigned short* Kt  = &sm[cur][0];
    const unsigned short* Vts = Kt + 8192;
    if (j <= tLow) step_two(j, Kt, Vts, j == tLow, j == tHigh);
    else           step_one(j, Kt, Vts, j == tHigh);
    cur ^= 1;
  }

#pragma unroll
  for (int t = 0; t < 8; t++)
#pragma unroll
    for (int r = 0; r < 4; r++) {
      int rgL = q0L + wave * 16 + quad * 4 + r;
      int rgH = q0H + wave * 16 + quad * 4 + r;
      AO[(size_t)(b * S_ + rgL) * HID_ + h * HD_ + t * 16 + l15] = f2bf(oacL[t][r] / oacEL[r]);
      AO[(size_t)(b * S_ + rgH) * HID_ + h * HD_ + t * 16 + l15] = f2bf(oacH[t][r] / oacEH[r]);
    }
}

extern "C" void kernel_launch(void* const* d_in, const int* in_sizes, int n_in,
                              void* d_out, int out_size, void* d_ws, size_t ws_size,
                              hipStream_t stream) {
  (void)in_sizes; (void)n_in; (void)out_size; (void)ws_size;
  const float* hidden = (const float*)d_in[0];
  const int*   pos    = (const int*)d_in[1];
  const float* Wqkv   = (const float*)d_in[2];
  const float* Wout   = (const float*)d_in[3];
  float* out = (float*)d_out;

  unsigned short* ws = (unsigned short*)d_ws;
  const size_t M1 = 1024 * 1024;
  unsigned short* hb  = ws;
  unsigned short* wqb = ws + 8 * M1;
  unsigned short* wob = ws + 14 * M1;
  unsigned short* Qb  = ws + 18 * M1;
  unsigned short* Kb  = ws + 26 * M1;
  unsigned short* Vt  = ws + 28 * M1;
  float2*         tab = (float2*)(ws + 30 * M1);   // 4096*64*8B = 2MB
  unsigned short* AO  = hb;

  k_cvt3<<<18432, 256, 0, stream>>>(hidden, hb, 2097152,
                                    Wqkv, wqb, 1572864,
                                    Wout, wob, 1048576);
  k_tab<<<1024, 256, 0, stream>>>(pos, tab);
  k_gemm_bt<0><<<dim3(32, 24), 256, 0, stream>>>(hb, wqb, Qb, Kb, Vt, nullptr, tab);
  k_attn<<<dim3(16, 32), 256, 0, stream>>>(Qb, Kb, Vt, AO);
  k_gemm_bt<1><<<dim3(32, 16), 256, 0, stream>>>(AO, wob, nullptr, nullptr, nullptr, out, nullptr);
}

// Round 10
// 289.962 us; speedup vs baseline: 3.4081x; 1.1544x over previous
//
#include <hip/hip_runtime.h>
#include <stdint.h>

#define S_    2048
#define HID_  2048
#define NH_   16
#define NKV_  4
#define HD_   128

using short4x = __attribute__((ext_vector_type(4))) short;
using short8  = __attribute__((ext_vector_type(8))) short;
using floatx4 = __attribute__((ext_vector_type(4))) float;

#define NEGBIG (-3.0e38f)
#define QSCL_  (0.08838834764831845f * 1.4426950408889634f)

__device__ __forceinline__ unsigned short f2bf(float x) {
  union { float f; unsigned u; } v; v.f = x;
  unsigned r = v.u + 0x7fffu + ((v.u >> 16) & 1u);
  return (unsigned short)(r >> 16);
}
__device__ __forceinline__ void ld_lds16(const void* g, void* l) {
  __builtin_amdgcn_global_load_lds(
      (const __attribute__((address_space(1))) unsigned*)g,
      (__attribute__((address_space(3))) unsigned*)l, 16, 0, 0);
}

// ---------------- fused fp32 -> bf16 convert of all three inputs ----------------
__global__ void k_cvt3(const float* __restrict__ s0, unsigned short* __restrict__ d0, int n0,
                       const float* __restrict__ s1, unsigned short* __restrict__ d1, int n1,
                       const float* __restrict__ s2, unsigned short* __restrict__ d2, int n2) {
  int i = blockIdx.x * blockDim.x + threadIdx.x;
  const float* s; unsigned short* d;
  if (i < n0) { s = s0; d = d0; }
  else if (i < n0 + n1) { s = s1; d = d1; i -= n0; }
  else { s = s2; d = d2; i -= n0 + n1; if (i >= n2) return; }
  float4 v = ((const float4*)s)[i];
  union { unsigned short us[4]; uint2 u2; } u;
  u.us[0] = f2bf(v.x); u.us[1] = f2bf(v.y); u.us[2] = f2bf(v.z); u.us[3] = f2bf(v.w);
  ((uint2*)d)[i] = u.u2;
}

// ---- bt-GEMM: C[m,n] = sum_k A[m,k]*B[n,k], 128x128 tile, BK=32 (m97 single-buf)
// Column-interleaved wave mapping: wave owns cols {c, c+16, c+64, c+80},
// c=(wave&1)*32, so the RoPE rotate pair (d, d+64) is (acc[i][j], acc[i][j+2])
// IN-THREAD (R9, verified). RoPE trig via HW v_sin/v_cos/v_fract single
// instructions (TRANS pipe) — NOT libm (R5: libm trig spilled the acc, 795us)
// and NOT a table (R9: 32 scattered 8B loads/thread cost ~15us + k_tab launch).
// Angle err ~2e-4 rad << bf16 quantization of the same values.
// EPI==0: QKV + clamp + in-thread RoPE (Q scaled). EPI==1: plain f32 store.
template <int EPI>
__global__ void __launch_bounds__(256)
k_gemm_bt(const unsigned short* __restrict__ A, const unsigned short* __restrict__ Bw,
          unsigned short* __restrict__ Qb, unsigned short* __restrict__ Kb,
          unsigned short* __restrict__ Vt, float* __restrict__ Of,
          const int* __restrict__ pos) {
  const int K = HID_;
  __shared__ __align__(16) unsigned short As[128 * 32];
  __shared__ __align__(16) unsigned short Bs[128 * 32];
  const int tid  = threadIdx.x;
  const int wave = tid >> 6, lane = tid & 63;
  const int quad = lane >> 4, l15 = lane & 15;
  const int wm = (wave >> 1) * 64;
  const int bc2 = (wave & 1) * 32;   // column sub-block base
  const int m0 = blockIdx.x * 128, n0 = blockIdx.y * 128;

  floatx4 acc[4][4] = {};

  const int srow = tid >> 2;
  const int scol = (tid & 3) * 8;
  const unsigned short* Ag0 = A  + (size_t)(m0 + srow)      * K + scol;
  const unsigned short* Ag1 = A  + (size_t)(m0 + 64 + srow) * K + scol;
  const unsigned short* Bg0 = Bw + (size_t)(n0 + srow)      * K + scol;
  const unsigned short* Bg1 = Bw + (size_t)(n0 + 64 + srow) * K + scol;
  unsigned short* lA0 = &As[tid * 8];
  unsigned short* lA1 = &As[2048 + tid * 8];
  unsigned short* lB0 = &Bs[tid * 8];
  unsigned short* lB1 = &Bs[2048 + tid * 8];

  for (int k0 = 0; k0 < K; k0 += 32) {
    __syncthreads();
    ld_lds16(Ag0 + k0, lA0);
    ld_lds16(Ag1 + k0, lA1);
    ld_lds16(Bg0 + k0, lB0);
    ld_lds16(Bg1 + k0, lB1);
    __syncthreads();
    short8 a[4], b[4];
#pragma unroll
    for (int i = 0; i < 4; i++) a[i] = *(const short8*)&As[(wm + i * 16 + l15) * 32 + quad * 8];
#pragma unroll
    for (int j = 0; j < 4; j++) {
      const int brow = bc2 + (j & 1) * 16 + (j >> 1) * 64;   // interleaved col map
      b[j] = *(const short8*)&Bs[(brow + l15) * 32 + quad * 8];
    }
#pragma unroll
    for (int i = 0; i < 4; i++)
#pragma unroll
      for (int j = 0; j < 4; j++)
        acc[i][j] = __builtin_amdgcn_mfma_f32_16x16x32_bf16(a[i], b[j], acc[i][j], 0, 0, 0);
  }

  if (EPI == 1) {
#pragma unroll
    for (int i = 0; i < 4; i++)
#pragma unroll
      for (int j = 0; j < 4; j++) {
        const int col = n0 + bc2 + (j & 1) * 16 + (j >> 1) * 64 + l15;
#pragma unroll
        for (int r = 0; r < 4; r++) {
          const int row = m0 + wm + i * 16 + quad * 4 + r;
          Of[(size_t)row * HID_ + col] = acc[i][j][r];
        }
      }
    return;
  }

  if (n0 >= HID_ + NKV_ * HD_) {
    // V tile: clamp + transposed store (no rope)
#pragma unroll
    for (int i = 0; i < 4; i++)
#pragma unroll
      for (int j = 0; j < 4; j++) {
        const int col = n0 + bc2 + (j & 1) * 16 + (j >> 1) * 64 + l15;
        const int oo = col - (HID_ + NKV_ * HD_);
        const int kvh = oo >> 7, d = oo & 127;
#pragma unroll
        for (int r = 0; r < 4; r++) {
          const int row = m0 + wm + i * 16 + quad * 4 + r;
          float x = fminf(fmaxf(acc[i][j][r], -8.0f), 8.0f);
          int bb = row >> 11, ss = row & 2047;
          Vt[((size_t)((bb * NKV_ + kvh) * HD_ + d) << 11) + ss] = f2bf(x);
        }
      }
    return;
  }

  // Q or K tile: in-thread RoPE (pair = acc[i][j], acc[i][j+2]); block-uniform
  const bool isQ = (n0 < HID_);
  const float oscale = isQ ? QSCL_ : 1.0f;
  // inv2p[j] = theta^(-d/64) / (2*pi): angle in REVOLUTIONS for v_sin/v_cos.
  // 0.29580575865 = ln(500000)/64 * log2(e);  0.15915494 = 1/(2*pi)
  float inv2p[2];
#pragma unroll
  for (int j = 0; j < 2; j++) {
    const float d = (float)(bc2 + j * 16 + l15);
    inv2p[j] = __builtin_amdgcn_exp2f(-d * 0.29580575865f) * 0.15915494309189535f;
  }
#pragma unroll
  for (int i = 0; i < 4; i++) {
    const int rowb = m0 + wm + i * 16 + quad * 4;
#pragma unroll
    for (int r = 0; r < 4; r++) {
      const int row = rowb + r;
      const float p = (float)pos[row];
#pragma unroll
      for (int j = 0; j < 2; j++) {
        const int dlo = bc2 + j * 16 + l15;   // in-head freq index, [0,64)
        const float rv = __builtin_amdgcn_fractf(p * inv2p[j]);
        const float cs = __builtin_amdgcn_cosf(rv);
        const float sn = __builtin_amdgcn_sinf(rv);
        const float x = fminf(fmaxf(acc[i][j][r],     -8.0f), 8.0f);
        const float y = fminf(fmaxf(acc[i][j + 2][r], -8.0f), 8.0f);
        const float lo = (x * cs - y * sn) * oscale;
        const float hi = (y * cs + x * sn) * oscale;
        if (isQ) {
          Qb[(size_t)row * HID_ + n0 + dlo]      = f2bf(lo);
          Qb[(size_t)row * HID_ + n0 + dlo + 64] = f2bf(hi);
        } else {
          const int cb = n0 - HID_;
          Kb[(size_t)row * (NKV_ * HD_) + cb + dlo]      = f2bf(lo);
          Kb[(size_t)row * (NKV_ * HD_) + cb + dlo + 64] = f2bf(hi);
        }
      }
    }
  }
}

// --- flash attention v7: XOR bank swizzle + defer-max + T5 setprio on MFMA ---
__global__ void __launch_bounds__(256, 2)
k_attn(const unsigned short* __restrict__ Qb, const unsigned short* __restrict__ Kb,
       const unsigned short* __restrict__ Vt, unsigned short* __restrict__ AO) {
  __shared__ __align__(16) unsigned short sm[2][16384];
  __shared__ __align__(16) unsigned short Pl[4][16][88];

  const int tid  = threadIdx.x;
  const int wave = tid >> 6, lane = tid & 63;
  const int quad = lane >> 4, l15 = lane & 15;
  const int tLow  = blockIdx.x;
  const int tHigh = 31 - tLow;
  const int q0L = tLow * 64, q0H = tHigh * 64;
  const int bh = blockIdx.y;
  const int b = bh >> 4, h = bh & 15;
  const int kvh = h >> 2;

  const int srow = tid >> 2;
  const int scolz = (((tid & 3) ^ ((tid >> 3) & 3)) * 8);
  const int qoff = ((quad ^ ((l15 >> 1) & 3)) * 8);

  {
    const unsigned short* qgL = Qb + (size_t)(b * S_ + q0L + srow) * HID_ + h * HD_ + scolz;
    const unsigned short* qgH = Qb + (size_t)(b * S_ + q0H + srow) * HID_ + h * HD_ + scolz;
#pragma unroll
    for (int i = 0; i < 4; i++) ld_lds16(qgL + i * 32, &sm[0][i * 2048 + tid * 8]);
#pragma unroll
    for (int i = 0; i < 4; i++) ld_lds16(qgH + i * 32, &sm[1][i * 2048 + tid * 8]);
  }
  __syncthreads();
  short8 qaL[4], qaH[4];
#pragma unroll
  for (int c = 0; c < 4; c++) {
    qaL[c] = *(const short8*)&sm[0][(c * 64 + wave * 16 + l15) * 32 + qoff];
    qaH[c] = *(const short8*)&sm[1][(c * 64 + wave * 16 + l15) * 32 + qoff];
  }
  __syncthreads();

  floatx4 oacL[8] = {}, oacH[8] = {};
  floatx4 oacEL = {}, oacEH = {};
  float mL = NEGBIG, mH = NEGBIG;

  const unsigned short* kgb = Kb + (size_t)b * S_ * (NKV_ * HD_) + kvh * HD_ + scolz;
  const unsigned short* vgb = Vt + (size_t)(b * NKV_ + kvh) * HD_ * S_;

  unsigned short* PlW = &Pl[wave][0][0];

  short8 ones;
#pragma unroll
  for (int i = 0; i < 8; i++) ones[i] = (short)0x3F80;

  auto stage = [&](int bufI, int j) {
    unsigned short* B = &sm[bufI][0];
    const unsigned short* kg = kgb + (size_t)(j * 64 + srow) * (NKV_ * HD_);
#pragma unroll
    for (int i = 0; i < 4; i++) ld_lds16(kg + i * 32, &B[i * 2048 + tid * 8]);
#pragma unroll
    for (int i = 0; i < 4; i++) {
      int c = i >> 1, rowd = (i & 1) * 64 + srow;
      ld_lds16(vgb + (size_t)rowd * S_ + j * 64 + c * 32 + scolz,
               &B[8192 + c * 4096 + (i & 1) * 2048 + tid * 8]);
    }
  };

  auto softmax_tile = [&](floatx4* sc, floatx4* oac, floatx4& oacE, float& m_run,
                          int q0, int j, bool diag, short8& pa0, short8& pa1) {
    if (diag) {
      const int rowq = q0 + wave * 16 + l15;
#pragma unroll
      for (int t = 0; t < 4; t++) {
        const int kb0 = j * 64 + t * 16 + quad * 4;
#pragma unroll
        for (int r = 0; r < 4; r++)
          if (kb0 + r > rowq) sc[t][r] = NEGBIG;
      }
    }
    float mx = sc[0][0];
#pragma unroll
    for (int t = 0; t < 4; t++)
#pragma unroll
      for (int r = 0; r < 4; r++) mx = fmaxf(mx, sc[t][r]);
    mx = fmaxf(mx, __shfl_xor(mx, 16));
    mx = fmaxf(mx, __shfl_xor(mx, 32));

    const float mo = m_run;
    if (__any(mx > mo + 8.0f)) {   // defer-max: rescale only on big jumps
      m_run = fmaxf(mo, mx);
      float alpha = __builtin_amdgcn_exp2f(mo - m_run);
      float al4[4];
#pragma unroll
      for (int r = 0; r < 4; r++) al4[r] = __shfl(alpha, quad * 4 + r, 16);
#pragma unroll
      for (int t = 0; t < 8; t++)
#pragma unroll
        for (int r = 0; r < 4; r++) oac[t][r] *= al4[r];
#pragma unroll
      for (int r = 0; r < 4; r++) oacE[r] *= al4[r];
    }
#pragma unroll
    for (int t = 0; t < 4; t++) {
      short4x pk;
#pragma unroll
      for (int r = 0; r < 4; r++)
        pk[r] = (short)f2bf(__builtin_amdgcn_exp2f(sc[t][r] - m_run));
      *(short4x*)&PlW[l15 * 88 + t * 16 + quad * 4] = pk;
    }
    pa0 = *(const short8*)&PlW[l15 * 88 + quad * 8];
    pa1 = *(const short8*)&PlW[l15 * 88 + 32 + quad * 8];
  };

  auto step_two = [&](int j, const unsigned short* Kt, const unsigned short* Vts,
                      bool diagL, bool diagH) {
    floatx4 scH[4] = {}, scL[4] = {};
    __builtin_amdgcn_s_setprio(1);
#pragma unroll
    for (int t = 0; t < 4; t++)
#pragma unroll
      for (int c = 0; c < 4; c++) {
        short8 ka = *(const short8*)&Kt[c * 2048 + (t * 16 + l15) * 32 + qoff];
        scH[t] = __builtin_amdgcn_mfma_f32_16x16x32_bf16(ka, qaH[c], scH[t], 0, 0, 0);
        scL[t] = __builtin_amdgcn_mfma_f32_16x16x32_bf16(ka, qaL[c], scL[t], 0, 0, 0);
      }
    __builtin_amdgcn_s_setprio(0);
    short8 paH0, paH1, paL0, paL1;
    softmax_tile(scH, oacH, oacEH, mH, q0H, j, diagH, paH0, paH1);
    softmax_tile(scL, oacL, oacEL, mL, q0L, j, diagL, paL0, paL1);
    __builtin_amdgcn_s_setprio(1);
#pragma unroll
    for (int t = 0; t < 8; t++) {
      short8 vb0 = *(const short8*)&Vts[(t * 16 + l15) * 32 + qoff];
      oacH[t] = __builtin_amdgcn_mfma_f32_16x16x32_bf16(paH0, vb0, oacH[t], 0, 0, 0);
      oacL[t] = __builtin_amdgcn_mfma_f32_16x16x32_bf16(paL0, vb0, oacL[t], 0, 0, 0);
      short8 vb1 = *(const short8*)&Vts[4096 + (t * 16 + l15) * 32 + qoff];
      oacH[t] = __builtin_amdgcn_mfma_f32_16x16x32_bf16(paH1, vb1, oacH[t], 0, 0, 0);
      oacL[t] = __builtin_amdgcn_mfma_f32_16x16x32_bf16(paL1, vb1, oacL[t], 0, 0, 0);
    }
    oacEH = __builtin_amdgcn_mfma_f32_16x16x32_bf16(paH0, ones, oacEH, 0, 0, 0);
    oacEH = __builtin_amdgcn_mfma_f32_16x16x32_bf16(paH1, ones, oacEH, 0, 0, 0);
    oacEL = __builtin_amdgcn_mfma_f32_16x16x32_bf16(paL0, ones, oacEL, 0, 0, 0);
    oacEL = __builtin_amdgcn_mfma_f32_16x16x32_bf16(paL1, ones, oacEL, 0, 0, 0);
    __builtin_amdgcn_s_setprio(0);
  };

  auto step_one = [&](int j, const unsigned short* Kt, const unsigned short* Vts, bool diagH) {
    floatx4 scH[4] = {};
    __builtin_amdgcn_s_setprio(1);
#pragma unroll
    for (int t = 0; t < 4; t++)
#pragma unroll
      for (int c = 0; c < 4; c++) {
        short8 ka = *(const short8*)&Kt[c * 2048 + (t * 16 + l15) * 32 + qoff];
        scH[t] = __builtin_amdgcn_mfma_f32_16x16x32_bf16(ka, qaH[c], scH[t], 0, 0, 0);
      }
    __builtin_amdgcn_s_setprio(0);
    short8 paH0, paH1;
    softmax_tile(scH, oacH, oacEH, mH, q0H, j, diagH, paH0, paH1);
    __builtin_amdgcn_s_setprio(1);
#pragma unroll
    for (int t = 0; t < 8; t++) {
      short8 vb0 = *(const short8*)&Vts[(t * 16 + l15) * 32 + qoff];
      oacH[t] = __builtin_amdgcn_mfma_f32_16x16x32_bf16(paH0, vb0, oacH[t], 0, 0, 0);
      short8 vb1 = *(const short8*)&Vts[4096 + (t * 16 + l15) * 32 + qoff];
      oacH[t] = __builtin_amdgcn_mfma_f32_16x16x32_bf16(paH1, vb1, oacH[t], 0, 0, 0);
    }
    oacEH = __builtin_amdgcn_mfma_f32_16x16x32_bf16(paH0, ones, oacEH, 0, 0, 0);
    oacEH = __builtin_amdgcn_mfma_f32_16x16x32_bf16(paH1, ones, oacEH, 0, 0, 0);
    __builtin_amdgcn_s_setprio(0);
  };

  stage(0, 0);
  int cur = 0;
  for (int j = 0; j <= tHigh; ++j) {
    __syncthreads();
    if (j < tHigh) stage(cur ^ 1, j + 1);
    const unsigned short* Kt  = &sm[cur][0];
    const unsigned short* Vts = Kt + 8192;
    if (j <= tLow) step_two(j, Kt, Vts, j == tLow, j == tHigh);
    else           step_one(j, Kt, Vts, j == tHigh);
    cur ^= 1;
  }

#pragma unroll
  for (int t = 0; t < 8; t++)
#pragma unroll
    for (int r = 0; r < 4; r++) {
      int rgL = q0L + wave * 16 + quad * 4 + r;
      int rgH = q0H + wave * 16 + quad * 4 + r;
      AO[(size_t)(b * S_ + rgL) * HID_ + h * HD_ + t * 16 + l15] = f2bf(oacL[t][r] / oacEL[r]);
      AO[(size_t)(b * S_ + rgH) * HID_ + h * HD_ + t * 16 + l15] = f2bf(oacH[t][r] / oacEH[r]);
    }
}

extern "C" void kernel_launch(void* const* d_in, const int* in_sizes, int n_in,
                              void* d_out, int out_size, void* d_ws, size_t ws_size,
                              hipStream_t stream) {
  (void)in_sizes; (void)n_in; (void)out_size; (void)ws_size;
  const float* hidden = (const float*)d_in[0];
  const int*   pos    = (const int*)d_in[1];
  const float* Wqkv   = (const float*)d_in[2];
  const float* Wout   = (const float*)d_in[3];
  float* out = (float*)d_out;

  unsigned short* ws = (unsigned short*)d_ws;
  const size_t M1 = 1024 * 1024;
  unsigned short* hb  = ws;
  unsigned short* wqb = ws + 8 * M1;
  unsigned short* wob = ws + 14 * M1;
  unsigned short* Qb  = ws + 18 * M1;
  unsigned short* Kb  = ws + 26 * M1;
  unsigned short* Vt  = ws + 28 * M1;
  unsigned short* AO  = hb;

  k_cvt3<<<18432, 256, 0, stream>>>(hidden, hb, 2097152,
                                    Wqkv, wqb, 1572864,
                                    Wout, wob, 1048576);
  k_gemm_bt<0><<<dim3(32, 24), 256, 0, stream>>>(hb, wqb, Qb, Kb, Vt, nullptr, pos);
  k_attn<<<dim3(16, 32), 256, 0, stream>>>(Qb, Kb, Vt, AO);
  k_gemm_bt<1><<<dim3(32, 16), 256, 0, stream>>>(AO, wob, nullptr, nullptr, nullptr, out, nullptr);
}